// Round 1
// baseline (425.398 us; speedup 1.0000x reference)
//
#include <hip/hip_runtime.h>
#include <stdint.h>

// Problem constants
#define N_ATOM 2048
#define K_TOT  32768        // N_ATOM * 16  (k = b*16 + f)
#define NKCH   32
#define KCHUNK 1024         // K_TOT / NKCH
#define BK     64

typedef __attribute__((ext_vector_type(8))) short bf16x8;
typedef __attribute__((ext_vector_type(4))) float f32x4;

typedef __attribute__((address_space(3))) uint32_t lds_u32;
typedef __attribute__((address_space(1))) uint32_t gbl_u32;

__device__ __forceinline__ void async_ld16(const void* g, void* l) {
  __builtin_amdgcn_global_load_lds((const gbl_u32*)g, (lds_u32*)l, 16, 0, 0);
}

// f32 -> bf16 round-to-nearest-even
__device__ __forceinline__ unsigned short f2bf(float x) {
  union { float f; uint32_t u; } v; v.f = x;
  uint32_t r = v.u + 0x7FFFu + ((v.u >> 16) & 1u);
  return (unsigned short)(r >> 16);
}

// ---------------------------------------------------------------------------
// Kernel 1: G[b][o][f] = sum_d node[b,d] * filters[o,f,d]   (bf16 output)
// As a GEMM: C[m=b][n=o*16+f] = node(2048x128) @ filters_rows(n,:128)^T
// filters flat: (o*16+f)*130 + d  ->  row n has k contiguous (stride 130).
// C row-major (row stride 2048) IS the [b][o][f] layout.
// ---------------------------------------------------------------------------
__global__ __launch_bounds__(256) void k_gt(const float* __restrict__ node,
                                            const float* __restrict__ filt,
                                            unsigned short* __restrict__ Gt) {
  __shared__ unsigned short As[128 * 136];  // [m][k] bf16, pad 136 (2-way max)
  __shared__ unsigned short Bs[128 * 136];  // [n][k] bf16
  const int t  = threadIdx.x;
  const int b0 = blockIdx.x * 128;
  const int n0 = blockIdx.y * 128;

  // stage A: node tile 128x128 f32 -> bf16 (float4 loads, coalesced)
#pragma unroll
  for (int rep = 0; rep < 16; ++rep) {
    int q = rep * 256 + t;          // float4 chunk id, 128 rows * 32 chunks
    int row = q >> 5, c4 = q & 31;
    float4 v = *(const float4*)(node + (size_t)(b0 + row) * 128 + c4 * 4);
    unsigned short* dst = &As[row * 136 + c4 * 4];
    dst[0] = f2bf(v.x); dst[1] = f2bf(v.y); dst[2] = f2bf(v.z); dst[3] = f2bf(v.w);
  }
  // stage B: filters rows (stride 130 -> only 8B aligned: float2 loads)
#pragma unroll
  for (int rep = 0; rep < 32; ++rep) {
    int q = rep * 256 + t;          // float2 chunk id, 128 rows * 64 chunks
    int row = q >> 6, c2 = q & 63;
    float2 v = *(const float2*)(filt + (size_t)(n0 + row) * 130 + c2 * 2);
    unsigned short* dst = &Bs[row * 136 + c2 * 2];
    dst[0] = f2bf(v.x); dst[1] = f2bf(v.y);
  }
  __syncthreads();

  const int w = t >> 6, l = t & 63;
  const int lm = l & 15, q4 = l >> 4;

  f32x4 acc[2][8];
#pragma unroll
  for (int ms = 0; ms < 2; ++ms)
#pragma unroll
    for (int ns = 0; ns < 8; ++ns)
      acc[ms][ns] = (f32x4){0.f, 0.f, 0.f, 0.f};

#pragma unroll
  for (int ks = 0; ks < 4; ++ks) {
    int ko = ks * 32 + q4 * 8;
    bf16x8 a[2], b[8];
#pragma unroll
    for (int ms = 0; ms < 2; ++ms) {
      int m = w * 32 + ms * 16 + lm;
      a[ms] = *(const bf16x8*)&As[m * 136 + ko];
    }
#pragma unroll
    for (int ns = 0; ns < 8; ++ns) {
      int n = ns * 16 + lm;
      b[ns] = *(const bf16x8*)&Bs[n * 136 + ko];
    }
#pragma unroll
    for (int ms = 0; ms < 2; ++ms)
#pragma unroll
      for (int ns = 0; ns < 8; ++ns)
        acc[ms][ns] = __builtin_amdgcn_mfma_f32_16x16x32_bf16(a[ms], b[ns], acc[ms][ns], 0, 0, 0);
  }

  // C/D layout: col = lane&15, row = (lane>>4)*4 + i
#pragma unroll
  for (int ms = 0; ms < 2; ++ms)
#pragma unroll
    for (int ns = 0; ns < 8; ++ns)
#pragma unroll
      for (int i = 0; i < 4; ++i) {
        int m = w * 32 + ms * 16 + q4 * 4 + i;
        int n = ns * 16 + lm;
        Gt[(size_t)(b0 + m) * 2048 + n0 + n] = f2bf(acc[ms][ns][i]);
      }
}

// ---------------------------------------------------------------------------
// Kernel 2: out[a][o] = sum_{f,j} bond[a,f,j] * filters[o,f,128+j]
// Also serves as the d_out initializer (harness poisons d_out each call).
// ---------------------------------------------------------------------------
__global__ __launch_bounds__(128) void k_bond(const float* __restrict__ bond,
                                              const float* __restrict__ filt,
                                              float* __restrict__ out) {
  __shared__ float bl[32];
  const int a = blockIdx.x, t = threadIdx.x;
  if (t < 32) bl[t] = bond[a * 32 + t];
  __syncthreads();
  float acc = 0.f;
  const float* fp = filt + (size_t)t * 2080 + 128;  // filters[o=t][f][128+j]
#pragma unroll
  for (int f = 0; f < 16; ++f)
    acc += bl[2 * f] * fp[f * 130] + bl[2 * f + 1] * fp[f * 130 + 1];
  out[(size_t)a * 128 + t] = acc;
}

// ---------------------------------------------------------------------------
// Kernel 3: out[a][o] += conn2d(2048 x 32768) @ G(32768 x 128), split-K.
// A = conn, k-contiguous fp32 rows, streamed with global_load_lds (16B) into
//     a 16B-chunk XOR-swizzled LDS tile (conflict-free frag reads, no pad).
// B = Gt[b][o][f] bf16, staged verbatim (contiguous) with global_load_lds.
// Split-K partials combined with fp32 atomicAdd into k2-initialized out.
// ---------------------------------------------------------------------------
__global__ __launch_bounds__(256) void k_main(const float* __restrict__ conn,
                                              const unsigned short* __restrict__ Gt,
                                              float* __restrict__ out) {
  __shared__ float Af[128 * BK];              // 32 KB, [m][chunk^swz]
  __shared__ unsigned short Bh[(BK / 16) * 128 * 16];  // 16 KB, [b_rel][o][f]

  const int t  = threadIdx.x;
  const int w  = t >> 6, l = t & 63;
  const int lm = l & 15, q4 = l >> 4;
  const int a0 = blockIdx.x * 128;
  const int kc = blockIdx.y * KCHUNK;

  f32x4 acc[2][8];
#pragma unroll
  for (int ms = 0; ms < 2; ++ms)
#pragma unroll
    for (int ns = 0; ns < 8; ++ns)
      acc[ms][ns] = (f32x4){0.f, 0.f, 0.f, 0.f};

  const float4* Af4 = (const float4*)Af;

  for (int it = 0; it < KCHUNK / BK; ++it) {
    const int k0 = kc + it * BK;
    __syncthreads();  // protect previous iteration's LDS reads

    // --- stage A: 128 rows x 64 f32 = 32KB, 8 rounds of 4KB ---
    // LDS 16B-slot s = r*256 + t : m = s>>4, c' = s&15 holds data chunk
    // c = c' ^ (m&15)  (XOR swizzle -> conflict-free b128 frag reads)
    {
      const int mt = t >> 4, cp = t & 15;
#pragma unroll
      for (int r = 0; r < 8; ++r) {
        int m = r * 16 + mt;
        int c = cp ^ (m & 15);
        const float* g = conn + (size_t)(a0 + m) * K_TOT + k0 + c * 4;
        void* lb = (void*)((char*)Af + r * 4096 + w * 1024);  // wave-uniform
        async_ld16(g, lb);
      }
    }
    // --- stage B: Gt chunk for k in [k0,k0+64) is 16KB contiguous ---
    {
      const unsigned short* gB = Gt + (size_t)k0 * 128;
#pragma unroll
      for (int r = 0; r < 4; ++r) {
        const void* g = gB + (size_t)(r * 256 + t) * 8;
        void* lb = (void*)((char*)Bh + r * 4096 + w * 1024);  // wave-uniform
        async_ld16(g, lb);
      }
    }
    __syncthreads();

    // --- compute: two 16x16x32 K-steps ---
#pragma unroll
    for (int kk = 0; kk < 2; ++kk) {
      // B fragments: k-octet = (fixed b, f0..f0+7) -> contiguous 16B
      const int b_rel = 2 * kk + (q4 >> 1);
      const int f0 = (q4 & 1) * 8;
      bf16x8 b[8];
#pragma unroll
      for (int ns = 0; ns < 8; ++ns) {
        int o = ns * 16 + lm;
        b[ns] = *(const bf16x8*)&Bh[b_rel * 2048 + o * 16 + f0];
      }
      // A fragments: 8 consecutive fp32 = swizzled chunks c0, c0+1; cvt->bf16
      const int c0 = kk * 8 + q4 * 2;
      bf16x8 a[2];
#pragma unroll
      for (int ms = 0; ms < 2; ++ms) {
        int m = w * 32 + ms * 16 + lm;
        float4 lo = Af4[m * 16 + (c0 ^ (m & 15))];
        float4 hi = Af4[m * 16 + ((c0 + 1) ^ (m & 15))];
        bf16x8 av;
        av[0] = (short)f2bf(lo.x); av[1] = (short)f2bf(lo.y);
        av[2] = (short)f2bf(lo.z); av[3] = (short)f2bf(lo.w);
        av[4] = (short)f2bf(hi.x); av[5] = (short)f2bf(hi.y);
        av[6] = (short)f2bf(hi.z); av[7] = (short)f2bf(hi.w);
        a[ms] = av;
      }
#pragma unroll
      for (int ms = 0; ms < 2; ++ms)
#pragma unroll
        for (int ns = 0; ns < 8; ++ns)
          acc[ms][ns] = __builtin_amdgcn_mfma_f32_16x16x32_bf16(a[ms], b[ns], acc[ms][ns], 0, 0, 0);
    }
  }

  // epilogue: split-K combine via fp32 atomics (16-lane coalesced segments)
#pragma unroll
  for (int ms = 0; ms < 2; ++ms)
#pragma unroll
    for (int ns = 0; ns < 8; ++ns)
#pragma unroll
      for (int i = 0; i < 4; ++i) {
        int m = w * 32 + ms * 16 + q4 * 4 + i;
        int n = ns * 16 + lm;
        atomicAdd(&out[(size_t)(a0 + m) * 128 + n], acc[ms][ns][i]);
      }
}

// ---------------------------------------------------------------------------
extern "C" void kernel_launch(void* const* d_in, const int* in_sizes, int n_in,
                              void* d_out, int out_size, void* d_ws, size_t ws_size,
                              hipStream_t stream) {
  const float* node = (const float*)d_in[0];  // (2048, 128)
  const float* conn = (const float*)d_in[1];  // (2048, 2048, 16)
  const float* bond = (const float*)d_in[2];  // (2048, 16, 2)
  const float* filt = (const float*)d_in[3];  // (128, 16, 130)
  float* out = (float*)d_out;                 // (2048, 128)

  if (ws_size < (size_t)N_ATOM * 2048 * sizeof(unsigned short)) return;  // need 8 MB
  unsigned short* Gt = (unsigned short*)d_ws;  // [b][o][f] bf16, 8 MB

  k_gt  <<<dim3(16, 16), 256, 0, stream>>>(node, filt, Gt);
  k_bond<<<dim3(2048),   128, 0, stream>>>(bond, filt, out);
  k_main<<<dim3(16, 32), 256, 0, stream>>>(conn, Gt, out);
}